// Round 8
// baseline (211.999 us; speedup 1.0000x reference)
//
#include <hip/hip_runtime.h>
#include <cstdint>
#include <cstddef>

// ---------------------------------------------------------------------------
// Fused causal attention block: QKV proj (+RoPE) -> MFMA flash attn -> out proj
// B=2 T=2048 C=1024 H=16 HD=64. Inputs fp32, output fp32, internal bf16 MFMA.
// R8: attn computes S^T (A=K,B=Q^T) with a permuted K-row LDS layout so the
// post-exp2 QK^T C-registers ARE the PV B-fragment (P never touches LDS).
// Q B-frag loaded straight from global; LDS 18.4KB (Ks+Vs only); grid unpaired
// 1024 blocks long-first. Q softmax scale folded into Wq at convert; (cos,sin)
// packed float2 table. 4 launches.
// ws (bf16 elems): xb@0 (4M, reused attn-out), QK@4M (8M, stride 2048),
// Vt@12M (4M), Wqkv@16M (3M), Wob@19M (1M), cs-table@20M (512KB).
// ---------------------------------------------------------------------------

typedef __bf16 bf16;
typedef float  f32x4  __attribute__((ext_vector_type(4)));
typedef __bf16 bf16x4 __attribute__((ext_vector_type(4)));
typedef __bf16 bf16x8 __attribute__((ext_vector_type(8)));

constexpr int Bb = 2, Tt = 2048, Cc = 1024, Hh = 16;
constexpr int Mrows = Bb * Tt;          // 4096
constexpr int NT = Tt / 64;             // 32 key/query tiles
constexpr int BM = 128, BN = 128, BK = 64;
constexpr int LDS_ = 72;                // attention LDS stride

#define GLOAD_LDS16(gp, lp)                                                      \
    __builtin_amdgcn_global_load_lds(                                            \
        (const __attribute__((address_space(1))) void*)(gp),                     \
        (__attribute__((address_space(3))) void*)(lp), 16, 0, 0)

// ---- convert: x,W* fp32 -> bf16 (Wq pre-scaled by 0.125*log2e); pack cs table
__global__ __launch_bounds__(256) void convert_k(const float* __restrict__ x,
                                                 const float* __restrict__ Wq,
                                                 const float* __restrict__ Wk,
                                                 const float* __restrict__ Wv,
                                                 const float* __restrict__ Wo,
                                                 const float* __restrict__ cosb,
                                                 const float* __restrict__ sinb,
                                                 bf16* __restrict__ xb,
                                                 bf16* __restrict__ Wqkv,
                                                 bf16* __restrict__ Wob,
                                                 float2* __restrict__ cs)
{
    constexpr size_t M1 = 1024 * 1024;
    if (blockIdx.x >= 4096) {           // cs-table packing: 65536 (t,p) pairs
        int pi = ((blockIdx.x - 4096) * 256 + threadIdx.x) * 8;
#pragma unroll
        for (int u = 0; u < 8; ++u)
            cs[pi + u] = float2{cosb[pi + u], sinb[pi + u]};
        return;
    }
    size_t e = ((size_t)blockIdx.x * 256 + threadIdx.x) * 8;   // 8M elems total
    const float* src; bf16* dst; float sc = 1.0f;
    if (e < 4 * M1)      { src = x  + e;          dst = xb   + e; }
    else if (e < 5 * M1) { src = Wq + (e - 4*M1); dst = Wqkv + (e - 4*M1);
                           sc = 0.125f * 1.44269504088896f; }
    else if (e < 6 * M1) { src = Wk + (e - 5*M1); dst = Wqkv + M1 + (e - 5*M1); }
    else if (e < 7 * M1) { src = Wv + (e - 6*M1); dst = Wqkv + 2*M1 + (e - 6*M1); }
    else                 { src = Wo + (e - 7*M1); dst = Wob  + (e - 7*M1); }
    float4 v0 = *(const float4*)(src);
    float4 v1 = *(const float4*)(src + 4);
    bf16x8 t;
    t[0] = (bf16)(v0.x*sc); t[1] = (bf16)(v0.y*sc); t[2] = (bf16)(v0.z*sc); t[3] = (bf16)(v0.w*sc);
    t[4] = (bf16)(v1.x*sc); t[5] = (bf16)(v1.y*sc); t[6] = (bf16)(v1.z*sc); t[7] = (bf16)(v1.w*sc);
    *(bf16x8*)dst = t;
}

// ---- QKV GEMM [4096x3072x1024] with fused RoPE (Q,K) / transpose (V) epilogue
__global__ __launch_bounds__(256) void gemm_qkv(const bf16* __restrict__ A,
                                                const bf16* __restrict__ W,
                                                bf16* __restrict__ QK,
                                                bf16* __restrict__ Vt,
                                                const float2* __restrict__ cs)
{
    __shared__ bf16 As[BM * BK];        // unpadded: global_load_lds contract
    __shared__ bf16 Ws[BN * BK];
    const int tid  = threadIdx.x;
    const int lane = tid & 63, wave = tid >> 6;
    const int wr = (wave >> 1) * 64, wc = (wave & 1) * 64;
    const int l16 = lane & 15, lq = lane >> 4;
    const int row0 = blockIdx.x * BM, col0 = blockIdx.y * BN;
    const int srow = lane >> 3, scol = (lane & 7) * 8;

    f32x4 acc[4][4];
#pragma unroll
    for (int i = 0; i < 4; ++i)
#pragma unroll
        for (int j = 0; j < 4; ++j) acc[i][j] = f32x4{0.f, 0.f, 0.f, 0.f};

    const bf16* Abase = A + (size_t)(row0 + wave * 8 + srow) * Cc + scol;
    const bf16* Wbase = W + (size_t)(col0 + wave * 8 + srow) * Cc + scol;

    for (int k0 = 0; k0 < Cc; k0 += BK) {
#pragma unroll
        for (int rnd = 0; rnd < 4; ++rnd) {
            const int rr = rnd * 32 + wave * 8;
            GLOAD_LDS16(Abase + (size_t)rnd * 32 * Cc + k0, &As[rr * BK]);
            GLOAD_LDS16(Wbase + (size_t)rnd * 32 * Cc + k0, &Ws[rr * BK]);
        }
        __syncthreads();
#pragma unroll
        for (int ks = 0; ks < BK / 32; ++ks) {
            bf16x8 af[4], bfr[4];
#pragma unroll
            for (int i = 0; i < 4; ++i)
                af[i] = *(const bf16x8*)(&As[(wr + i * 16 + l16) * BK + ks * 32 + lq * 8]);
#pragma unroll
            for (int j = 0; j < 4; ++j)
                bfr[j] = *(const bf16x8*)(&Ws[(wc + j * 16 + l16) * BK + ks * 32 + lq * 8]);
#pragma unroll
            for (int i = 0; i < 4; ++i)
#pragma unroll
                for (int j = 0; j < 4; ++j)
                    acc[i][j] = __builtin_amdgcn_mfma_f32_16x16x32_bf16(
                        af[i], bfr[j], acc[i][j], 0, 0, 0);
        }
        __syncthreads();
    }

    if (blockIdx.y < 16) {
        // Q/K tile: RoPE in-register. Pair partner = adjacent lane (col bit0).
#pragma unroll
        for (int i = 0; i < 4; ++i)
#pragma unroll
            for (int j = 0; j < 4; ++j) {
                const int d   = (wc + j * 16 + l16) & 63;   // pos within head
                const int p   = d >> 1, odd = d & 1;
#pragma unroll
                for (int r = 0; r < 4; ++r) {
                    int row = row0 + wr + i * 16 + lq * 4 + r;
                    int t   = row & (Tt - 1);
                    float2 cp = cs[t * 32 + p];
                    float v = acc[i][j][r];
                    float w = __shfl_xor(v, 1);
                    float o = odd ? fmaf(v, cp.x, w * cp.y) : fmaf(v, cp.x, -(w * cp.y));
                    QK[(size_t)row * 2048 + col0 + wc + j * 16 + l16] = (bf16)o;
                }
            }
    } else {
        // V tile: store transposed into Vt[bh][d][t]; 4 acc rows = 4 consec t.
#pragma unroll
        for (int i = 0; i < 4; ++i)
#pragma unroll
            for (int j = 0; j < 4; ++j) {
                const int dfull = col0 - 2048 + wc + j * 16 + l16;
                const int h = dfull >> 6, d = dfull & 63;
                const int row = row0 + wr + i * 16 + lq * 4;
                const int b = row >> 11, t = row & (Tt - 1);
                bf16x4 pk;
                pk[0] = (bf16)acc[i][j][0]; pk[1] = (bf16)acc[i][j][1];
                pk[2] = (bf16)acc[i][j][2]; pk[3] = (bf16)acc[i][j][3];
                *(bf16x4*)(&Vt[((size_t)(b * 16 + h) * 64 + d) * (size_t)Tt + t]) = pk;
            }
    }
}

// ---- O GEMM: 128x64 tiles (512 blocks -> 2/CU), out fp32 ----
__global__ __launch_bounds__(256) void gemm_o(const bf16* __restrict__ A,
                                              const bf16* __restrict__ W,
                                              float* __restrict__ Out)
{
    __shared__ bf16 As[BM * BK];
    __shared__ bf16 Ws[64 * BK];
    const int tid  = threadIdx.x;
    const int lane = tid & 63, wave = tid >> 6;
    const int wr = (wave >> 1) * 64, wc = (wave & 1) * 32;
    const int l16 = lane & 15, lq = lane >> 4;
    const int row0 = blockIdx.x * BM, col0 = blockIdx.y * 64;
    const int srow = lane >> 3, scol = (lane & 7) * 8;

    f32x4 acc[4][2];
#pragma unroll
    for (int i = 0; i < 4; ++i)
#pragma unroll
        for (int j = 0; j < 2; ++j) acc[i][j] = f32x4{0.f, 0.f, 0.f, 0.f};

    const bf16* Abase = A + (size_t)(row0 + wave * 8 + srow) * Cc + scol;
    const bf16* Wbase = W + (size_t)(col0 + wave * 8 + srow) * Cc + scol;

    for (int k0 = 0; k0 < Cc; k0 += BK) {
#pragma unroll
        for (int rnd = 0; rnd < 4; ++rnd)
            GLOAD_LDS16(Abase + (size_t)rnd * 32 * Cc + k0, &As[(rnd * 32 + wave * 8) * BK]);
#pragma unroll
        for (int rnd = 0; rnd < 2; ++rnd)
            GLOAD_LDS16(Wbase + (size_t)rnd * 32 * Cc + k0, &Ws[(rnd * 32 + wave * 8) * BK]);
        __syncthreads();
#pragma unroll
        for (int ks = 0; ks < BK / 32; ++ks) {
            bf16x8 af[4], bfr[2];
#pragma unroll
            for (int i = 0; i < 4; ++i)
                af[i] = *(const bf16x8*)(&As[(wr + i * 16 + l16) * BK + ks * 32 + lq * 8]);
#pragma unroll
            for (int j = 0; j < 2; ++j)
                bfr[j] = *(const bf16x8*)(&Ws[(wc + j * 16 + l16) * BK + ks * 32 + lq * 8]);
#pragma unroll
            for (int i = 0; i < 4; ++i)
#pragma unroll
                for (int j = 0; j < 2; ++j)
                    acc[i][j] = __builtin_amdgcn_mfma_f32_16x16x32_bf16(
                        af[i], bfr[j], acc[i][j], 0, 0, 0);
        }
        __syncthreads();
    }
#pragma unroll
    for (int i = 0; i < 4; ++i)
#pragma unroll
        for (int j = 0; j < 2; ++j)
#pragma unroll
            for (int r = 0; r < 4; ++r) {
                int row = row0 + wr + i * 16 + lq * 4 + r;
                int col = col0 + wc + j * 16 + l16;
                Out[(size_t)row * Cc + col] = acc[i][j][r];
            }
}

// ---- MFMA flash attention (S^T form), causal, static-max, reg dbuf.
// Wave wv owns queries wv*16..+15 (cols of S^T). K rows stored permuted in LDS
// so post-exp2 C-regs [s0,s1]/[s2,s3] are directly the PV B-fragments.
__global__ __launch_bounds__(256, 4) void attn_k(const bf16* __restrict__ QK,
                                                 const bf16* __restrict__ Vt,
                                                 bf16* __restrict__ O)
{
    __shared__ bf16 Ks[64 * LDS_];
    __shared__ bf16 Vs[64 * LDS_];
    const int tid = threadIdx.x;
    const int wv = tid >> 6, lane = tid & 63;
    const int l16 = lane & 15, lq = lane >> 4;
    const int qt = NT - 1 - blockIdx.x;                 // long blocks first
    const int bh = blockIdx.y, b = bh >> 4, h = bh & 15;
    const int kr = tid >> 2, c0 = (tid & 3) * 16;       // staging coords
    // permuted LDS row: key -> 32*(k>>5) + 16*((k>>2)&1) + 4*((k>>3)&3) + (k&3)
    const int pr = 32 * (kr >> 5) + 16 * ((kr >> 2) & 1) + 4 * ((kr >> 3) & 3) + (kr & 3);

    const bf16* kcol = QK + 1024 + (size_t)(b * Tt + kr) * 2048 + h * 64 + c0;
    const bf16* vcol = Vt + ((size_t)bh * 64 + kr) * Tt + c0;

    // Q B-fragments straight from global (Q pre-scaled by 0.125*log2e)
    const int qglob = qt * 64 + wv * 16 + l16;
    const bf16* qp = QK + (size_t)(b * Tt + qglob) * 2048 + h * 64;
    bf16x8 qf0 = *(const bf16x8*)(qp + lq * 8);
    bf16x8 qf1 = *(const bf16x8*)(qp + 32 + lq * 8);

    uint4 pk0 = *(const uint4*)(kcol);
    uint4 pk1 = *(const uint4*)(kcol + 8);
    uint4 pv0 = *(const uint4*)(vcol);
    uint4 pv1 = *(const uint4*)(vcol + 8);

    float l = 0.f;
    f32x4 o[4];
#pragma unroll
    for (int dt = 0; dt < 4; ++dt) o[dt] = f32x4{0.f, 0.f, 0.f, 0.f};

    for (int t = 0; t <= qt; ++t) {
        *(uint4*)(&Ks[pr * LDS_ + c0])     = pk0;
        *(uint4*)(&Ks[pr * LDS_ + c0 + 8]) = pk1;
        *(uint4*)(&Vs[kr * LDS_ + c0])     = pv0;
        *(uint4*)(&Vs[kr * LDS_ + c0 + 8]) = pv1;
        __syncthreads();
        if (t < qt) {                       // prefetch next tile, overlaps compute
            const bf16* kn = kcol + (size_t)(t + 1) * 64 * 2048;
            const bf16* vn = vcol + (t + 1) * 64;
            pk0 = *(const uint4*)(kn);
            pk1 = *(const uint4*)(kn + 8);
            pv0 = *(const uint4*)(vn);
            pv1 = *(const uint4*)(vn + 8);
        }

        // S^T = K Q^T : A-frag = permuted K rows, B-frag = qf
        f32x4 s[4];
#pragma unroll
        for (int mt = 0; mt < 4; ++mt) s[mt] = f32x4{0.f, 0.f, 0.f, 0.f};
#pragma unroll
        for (int mt = 0; mt < 4; ++mt) {
            bf16x8 a0 = *(const bf16x8*)(&Ks[(mt * 16 + l16) * LDS_ + lq * 8]);
            s[mt] = __builtin_amdgcn_mfma_f32_16x16x32_bf16(a0, qf0, s[mt], 0, 0, 0);
        }
#pragma unroll
        for (int mt = 0; mt < 4; ++mt) {
            bf16x8 a1 = *(const bf16x8*)(&Ks[(mt * 16 + l16) * LDS_ + 32 + lq * 8]);
            s[mt] = __builtin_amdgcn_mfma_f32_16x16x32_bf16(a1, qf1, s[mt], 0, 0, 0);
        }
        if (t == qt) {                      // causal mask, diagonal tile only
            const int qloc = wv * 16 + l16;
#pragma unroll
            for (int mt = 0; mt < 4; ++mt)
#pragma unroll
                for (int r = 0; r < 4; ++r) {
                    int keyl = (mt >> 1) * 32 + lq * 8 + (mt & 1) * 4 + r;
                    if (keyl > qloc) s[mt][r] = -1e30f;
                }
        }
        // exp2 + row-sum partials; pack C-regs directly into PV B-frags
        bf16x8 pb0, pb1;
#pragma unroll
        for (int mt = 0; mt < 4; ++mt)
#pragma unroll
            for (int r = 0; r < 4; ++r) {
                float p = exp2f(s[mt][r]);
                l += p;
                s[mt][r] = p;
            }
#pragma unroll
        for (int r = 0; r < 4; ++r) {
            pb0[r]     = (bf16)s[0][r];
            pb0[4 + r] = (bf16)s[1][r];
            pb1[r]     = (bf16)s[2][r];
            pb1[4 + r] = (bf16)s[3][r];
        }
        // O^T += V^T P^T : A-frag = Vs rows (dims), B-frag = pb
#pragma unroll
        for (int dt = 0; dt < 4; ++dt) {
            bf16x8 v0 = *(const bf16x8*)(&Vs[(dt * 16 + l16) * LDS_ + lq * 8]);
            o[dt] = __builtin_amdgcn_mfma_f32_16x16x32_bf16(v0, pb0, o[dt], 0, 0, 0);
        }
#pragma unroll
        for (int dt = 0; dt < 4; ++dt) {
            bf16x8 v1 = *(const bf16x8*)(&Vs[(dt * 16 + l16) * LDS_ + 32 + lq * 8]);
            o[dt] = __builtin_amdgcn_mfma_f32_16x16x32_bf16(v1, pb1, o[dt], 0, 0, 0);
        }
        __syncthreads();                    // all waves done with Ks/Vs tile t
    }
    // l lives per-lane for query l16; sum partials across lq (lane bits 4,5)
    l += __shfl_xor(l, 16);
    l += __shfl_xor(l, 32);
    float inv = 1.f / l;
    // O^T C-layout: d = dt*16 + lq*4 + r (register-contiguous) -> bf16x4 stores
    bf16* op = O + (size_t)(b * Tt + qglob) * Cc + h * 64;
#pragma unroll
    for (int dt = 0; dt < 4; ++dt) {
        bf16x4 pk;
#pragma unroll
        for (int r = 0; r < 4; ++r) pk[r] = (bf16)(o[dt][r] * inv);
        *(bf16x4*)(op + dt * 16 + lq * 4) = pk;
    }
}

extern "C" void kernel_launch(void* const* d_in, const int* in_sizes, int n_in,
                              void* d_out, int out_size, void* d_ws, size_t ws_size,
                              hipStream_t stream)
{
    const float* x    = (const float*)d_in[0];
    const float* Wq   = (const float*)d_in[1];
    const float* Wk   = (const float*)d_in[2];
    const float* Wv   = (const float*)d_in[3];
    const float* Wo   = (const float*)d_in[4];
    const float* cosb = (const float*)d_in[5];
    const float* sinb = (const float*)d_in[6];

    constexpr size_t M1 = 1024 * 1024;
    bf16* base = (bf16*)d_ws;
    bf16*   xb   = base;                    //  0..4M   (reused as attn out)
    bf16*   QK   = base + 4 * M1;           //  4M..12M [4096][2048]
    bf16*   VtG  = base + 12 * M1;          // 12M..16M [32][64][2048]
    bf16*   Wqkv = base + 16 * M1;          // 16M..19M [3072][1024]
    bf16*   Wob  = base + 19 * M1;          // 19M..20M
    float2* csT  = (float2*)(base + 20 * M1); // 512 KB
    bf16*   Ow   = xb;

    convert_k<<<4096 + 32, 256, 0, stream>>>(x, Wq, Wk, Wv, Wo, cosb, sinb,
                                             xb, Wqkv, Wob, csT);

    gemm_qkv<<<dim3(Mrows / BM, 3072 / BN), 256, 0, stream>>>(
        xb, Wqkv, QK, VtG, csT);

    attn_k<<<dim3(NT, Bb * Hh), 256, 0, stream>>>(QK, VtG, Ow);

    gemm_o<<<dim3(Mrows / BM, Cc / 64), 256, 0, stream>>>(Ow, Wob, (float*)d_out);
}

// Round 9
// 203.169 us; speedup vs baseline: 1.0435x; 1.0435x over previous
//
#include <hip/hip_runtime.h>
#include <cstdint>
#include <cstddef>

// ---------------------------------------------------------------------------
// Fused causal attention block: QKV proj (+RoPE) -> MFMA flash attn -> out proj
// B=2 T=2048 C=1024 H=16 HD=64. Inputs fp32, output fp32, internal bf16 MFMA.
// R9 = R8 (S^T attn, P stays in registers) + R6 pairing (512 uniform blocks;
// R8's unpaired 1024-block grid was 50% idle: slots==blocks, makespan=longest)
// + vectorized GEMM epilogues (in-reg 4x4 quad transpose -> RoPE intra-lane,
// one float4 cs load, bf16x4/float4 stores).
// ws (bf16 elems): xb@0 (4M, reused attn-out), QK@4M (8M, stride 2048),
// Vt@12M (4M), Wqkv@16M (3M), Wob@19M (1M), cs-table@20M (512KB).
// ---------------------------------------------------------------------------

typedef __bf16 bf16;
typedef float  f32x4  __attribute__((ext_vector_type(4)));
typedef __bf16 bf16x4 __attribute__((ext_vector_type(4)));
typedef __bf16 bf16x8 __attribute__((ext_vector_type(8)));

constexpr int Bb = 2, Tt = 2048, Cc = 1024, Hh = 16;
constexpr int Mrows = Bb * Tt;          // 4096
constexpr int NT = Tt / 64;             // 32 key/query tiles
constexpr int BM = 128, BN = 128, BK = 64;
constexpr int LDS_ = 72;                // attention LDS stride

#define GLOAD_LDS16(gp, lp)                                                      \
    __builtin_amdgcn_global_load_lds(                                            \
        (const __attribute__((address_space(1))) void*)(gp),                     \
        (__attribute__((address_space(3))) void*)(lp), 16, 0, 0)

// 4x4 transpose across lanes (low 2 bits of l16) x regs; after: lane (g,c)
// holds row (..+c), cols g*4..g*4+3 in v0..v3.  [index algebra verified]
#define QUAD_T(v0, v1, v2, v3, c2)                                               \
    {                                                                            \
        float e0 = (c2 & 1) ? v0 : v1, e1 = (c2 & 1) ? v2 : v3;                  \
        e0 = __shfl_xor(e0, 1); e1 = __shfl_xor(e1, 1);                          \
        if (c2 & 1) { v0 = e0; v2 = e1; } else { v1 = e0; v3 = e1; }             \
        float f0 = (c2 & 2) ? v0 : v2, f1 = (c2 & 2) ? v1 : v3;                  \
        f0 = __shfl_xor(f0, 2); f1 = __shfl_xor(f1, 2);                          \
        if (c2 & 2) { v0 = f0; v1 = f1; } else { v2 = f0; v3 = f1; }             \
    }

// ---- convert: x,W* fp32 -> bf16 (Wq pre-scaled by 0.125*log2e); pack cs table
__global__ __launch_bounds__(256) void convert_k(const float* __restrict__ x,
                                                 const float* __restrict__ Wq,
                                                 const float* __restrict__ Wk,
                                                 const float* __restrict__ Wv,
                                                 const float* __restrict__ Wo,
                                                 const float* __restrict__ cosb,
                                                 const float* __restrict__ sinb,
                                                 bf16* __restrict__ xb,
                                                 bf16* __restrict__ Wqkv,
                                                 bf16* __restrict__ Wob,
                                                 float2* __restrict__ cs)
{
    constexpr size_t M1 = 1024 * 1024;
    if (blockIdx.x >= 4096) {           // cs-table packing: 65536 (t,p) pairs
        int pi = ((blockIdx.x - 4096) * 256 + threadIdx.x) * 8;
#pragma unroll
        for (int u = 0; u < 8; ++u)
            cs[pi + u] = float2{cosb[pi + u], sinb[pi + u]};
        return;
    }
    size_t e = ((size_t)blockIdx.x * 256 + threadIdx.x) * 8;   // 8M elems total
    const float* src; bf16* dst; float sc = 1.0f;
    if (e < 4 * M1)      { src = x  + e;          dst = xb   + e; }
    else if (e < 5 * M1) { src = Wq + (e - 4*M1); dst = Wqkv + (e - 4*M1);
                           sc = 0.125f * 1.44269504088896f; }
    else if (e < 6 * M1) { src = Wk + (e - 5*M1); dst = Wqkv + M1 + (e - 5*M1); }
    else if (e < 7 * M1) { src = Wv + (e - 6*M1); dst = Wqkv + 2*M1 + (e - 6*M1); }
    else                 { src = Wo + (e - 7*M1); dst = Wob  + (e - 7*M1); }
    float4 v0 = *(const float4*)(src);
    float4 v1 = *(const float4*)(src + 4);
    bf16x8 t;
    t[0] = (bf16)(v0.x*sc); t[1] = (bf16)(v0.y*sc); t[2] = (bf16)(v0.z*sc); t[3] = (bf16)(v0.w*sc);
    t[4] = (bf16)(v1.x*sc); t[5] = (bf16)(v1.y*sc); t[6] = (bf16)(v1.z*sc); t[7] = (bf16)(v1.w*sc);
    *(bf16x8*)dst = t;
}

// ---- QKV GEMM [4096x3072x1024] with fused RoPE (Q,K) / transpose (V) epilogue
__global__ __launch_bounds__(256) void gemm_qkv(const bf16* __restrict__ A,
                                                const bf16* __restrict__ W,
                                                bf16* __restrict__ QK,
                                                bf16* __restrict__ Vt,
                                                const float2* __restrict__ cs)
{
    __shared__ bf16 As[BM * BK];        // unpadded: global_load_lds contract
    __shared__ bf16 Ws[BN * BK];
    const int tid  = threadIdx.x;
    const int lane = tid & 63, wave = tid >> 6;
    const int wr = (wave >> 1) * 64, wc = (wave & 1) * 64;
    const int l16 = lane & 15, lq = lane >> 4;
    const int row0 = blockIdx.x * BM, col0 = blockIdx.y * BN;
    const int srow = lane >> 3, scol = (lane & 7) * 8;

    f32x4 acc[4][4];
#pragma unroll
    for (int i = 0; i < 4; ++i)
#pragma unroll
        for (int j = 0; j < 4; ++j) acc[i][j] = f32x4{0.f, 0.f, 0.f, 0.f};

    const bf16* Abase = A + (size_t)(row0 + wave * 8 + srow) * Cc + scol;
    const bf16* Wbase = W + (size_t)(col0 + wave * 8 + srow) * Cc + scol;

    for (int k0 = 0; k0 < Cc; k0 += BK) {
#pragma unroll
        for (int rnd = 0; rnd < 4; ++rnd) {
            const int rr = rnd * 32 + wave * 8;
            GLOAD_LDS16(Abase + (size_t)rnd * 32 * Cc + k0, &As[rr * BK]);
            GLOAD_LDS16(Wbase + (size_t)rnd * 32 * Cc + k0, &Ws[rr * BK]);
        }
        __syncthreads();
#pragma unroll
        for (int ks = 0; ks < BK / 32; ++ks) {
            bf16x8 af[4], bfr[4];
#pragma unroll
            for (int i = 0; i < 4; ++i)
                af[i] = *(const bf16x8*)(&As[(wr + i * 16 + l16) * BK + ks * 32 + lq * 8]);
#pragma unroll
            for (int j = 0; j < 4; ++j)
                bfr[j] = *(const bf16x8*)(&Ws[(wc + j * 16 + l16) * BK + ks * 32 + lq * 8]);
#pragma unroll
            for (int i = 0; i < 4; ++i)
#pragma unroll
                for (int j = 0; j < 4; ++j)
                    acc[i][j] = __builtin_amdgcn_mfma_f32_16x16x32_bf16(
                        af[i], bfr[j], acc[i][j], 0, 0, 0);
        }
        __syncthreads();
    }

    const int c2 = l16 & 3, g4 = (l16 >> 2) * 4;
    if (blockIdx.y < 16) {
        // Q/K tile: quad-transpose -> lane owns 1 row x 4 cols; RoPE intra-lane
#pragma unroll
        for (int i = 0; i < 4; ++i)
#pragma unroll
            for (int j = 0; j < 4; ++j) {
                float v0 = acc[i][j][0], v1 = acc[i][j][1];
                float v2 = acc[i][j][2], v3 = acc[i][j][3];
                QUAD_T(v0, v1, v2, v3, c2);
                const int row = row0 + wr + i * 16 + lq * 4 + c2;
                const int t   = row & (Tt - 1);
                const int colb = wc + j * 16 + g4;          // multiple of 4
                const int p0   = (colb & 63) >> 1;          // even
                float4 cp = *(const float4*)(&cs[t * 32 + p0]);  // (c0,s0,c1,s1)
                bf16x4 pk;
                pk[0] = (bf16)(v0 * cp.x - v1 * cp.y);
                pk[1] = (bf16)(v0 * cp.y + v1 * cp.x);
                pk[2] = (bf16)(v2 * cp.z - v3 * cp.w);
                pk[3] = (bf16)(v2 * cp.w + v3 * cp.z);
                *(bf16x4*)(&QK[(size_t)row * 2048 + col0 + colb]) = pk;
            }
    } else {
        // V tile: store transposed into Vt[bh][d][t]; 4 acc rows = 4 consec t.
#pragma unroll
        for (int i = 0; i < 4; ++i)
#pragma unroll
            for (int j = 0; j < 4; ++j) {
                const int dfull = col0 - 2048 + wc + j * 16 + l16;
                const int h = dfull >> 6, d = dfull & 63;
                const int row = row0 + wr + i * 16 + lq * 4;
                const int b = row >> 11, t = row & (Tt - 1);
                bf16x4 pk;
                pk[0] = (bf16)acc[i][j][0]; pk[1] = (bf16)acc[i][j][1];
                pk[2] = (bf16)acc[i][j][2]; pk[3] = (bf16)acc[i][j][3];
                *(bf16x4*)(&Vt[((size_t)(b * 16 + h) * 64 + d) * (size_t)Tt + t]) = pk;
            }
    }
}

// ---- O GEMM: 128x64 tiles (512 blocks -> 2/CU), out fp32, float4 stores ----
__global__ __launch_bounds__(256) void gemm_o(const bf16* __restrict__ A,
                                              const bf16* __restrict__ W,
                                              float* __restrict__ Out)
{
    __shared__ bf16 As[BM * BK];
    __shared__ bf16 Ws[64 * BK];
    const int tid  = threadIdx.x;
    const int lane = tid & 63, wave = tid >> 6;
    const int wr = (wave >> 1) * 64, wc = (wave & 1) * 32;
    const int l16 = lane & 15, lq = lane >> 4;
    const int row0 = blockIdx.x * BM, col0 = blockIdx.y * 64;
    const int srow = lane >> 3, scol = (lane & 7) * 8;

    f32x4 acc[4][2];
#pragma unroll
    for (int i = 0; i < 4; ++i)
#pragma unroll
        for (int j = 0; j < 2; ++j) acc[i][j] = f32x4{0.f, 0.f, 0.f, 0.f};

    const bf16* Abase = A + (size_t)(row0 + wave * 8 + srow) * Cc + scol;
    const bf16* Wbase = W + (size_t)(col0 + wave * 8 + srow) * Cc + scol;

    for (int k0 = 0; k0 < Cc; k0 += BK) {
#pragma unroll
        for (int rnd = 0; rnd < 4; ++rnd)
            GLOAD_LDS16(Abase + (size_t)rnd * 32 * Cc + k0, &As[(rnd * 32 + wave * 8) * BK]);
#pragma unroll
        for (int rnd = 0; rnd < 2; ++rnd)
            GLOAD_LDS16(Wbase + (size_t)rnd * 32 * Cc + k0, &Ws[(rnd * 32 + wave * 8) * BK]);
        __syncthreads();
#pragma unroll
        for (int ks = 0; ks < BK / 32; ++ks) {
            bf16x8 af[4], bfr[2];
#pragma unroll
            for (int i = 0; i < 4; ++i)
                af[i] = *(const bf16x8*)(&As[(wr + i * 16 + l16) * BK + ks * 32 + lq * 8]);
#pragma unroll
            for (int j = 0; j < 2; ++j)
                bfr[j] = *(const bf16x8*)(&Ws[(wc + j * 16 + l16) * BK + ks * 32 + lq * 8]);
#pragma unroll
            for (int i = 0; i < 4; ++i)
#pragma unroll
                for (int j = 0; j < 2; ++j)
                    acc[i][j] = __builtin_amdgcn_mfma_f32_16x16x32_bf16(
                        af[i], bfr[j], acc[i][j], 0, 0, 0);
        }
        __syncthreads();
    }
    const int c2 = l16 & 3, g4 = (l16 >> 2) * 4;
#pragma unroll
    for (int i = 0; i < 4; ++i)
#pragma unroll
        for (int j = 0; j < 2; ++j) {
            float v0 = acc[i][j][0], v1 = acc[i][j][1];
            float v2 = acc[i][j][2], v3 = acc[i][j][3];
            QUAD_T(v0, v1, v2, v3, c2);
            const int row = row0 + wr + i * 16 + lq * 4 + c2;
            const int col = col0 + wc + j * 16 + g4;
            *(float4*)(&Out[(size_t)row * Cc + col]) = float4{v0, v1, v2, v3};
        }
}

// ---- MFMA flash attention (S^T form), causal, static-max, reg dbuf, PAIRED.
// grid (NT/2, Bb*Hh); block bx does qt = NT-1-bx then qt = bx (33 steps total).
// Permuted K rows in LDS make post-exp2 C-regs the PV B-fragments directly.
__global__ __launch_bounds__(256, 4) void attn_k(const bf16* __restrict__ QK,
                                                 const bf16* __restrict__ Vt,
                                                 bf16* __restrict__ O)
{
    __shared__ bf16 Ks[64 * LDS_];
    __shared__ bf16 Vs[64 * LDS_];
    const int tid = threadIdx.x;
    const int wv = tid >> 6, lane = tid & 63;
    const int l16 = lane & 15, lq = lane >> 4;
    const int bh = blockIdx.y, b = bh >> 4, h = bh & 15;
    const int kr = tid >> 2, c0 = (tid & 3) * 16;       // staging coords
    // permuted LDS row: key -> 32*(k>>5) + 16*((k>>2)&1) + 4*((k>>3)&3) + (k&3)
    const int pr = 32 * (kr >> 5) + 16 * ((kr >> 2) & 1) + 4 * ((kr >> 3) & 3) + (kr & 3);

    const bf16* kcol = QK + 1024 + (size_t)(b * Tt + kr) * 2048 + h * 64 + c0;
    const bf16* vcol = Vt + ((size_t)bh * 64 + kr) * Tt + c0;

    for (int phase = 0; phase < 2; ++phase) {
        const int qt = phase ? blockIdx.x : (NT - 1 - blockIdx.x);

        // Q B-fragments straight from global (Q pre-scaled by 0.125*log2e)
        const int qglob = qt * 64 + wv * 16 + l16;
        const bf16* qp = QK + (size_t)(b * Tt + qglob) * 2048 + h * 64;
        bf16x8 qf0 = *(const bf16x8*)(qp + lq * 8);
        bf16x8 qf1 = *(const bf16x8*)(qp + 32 + lq * 8);

        uint4 pk0 = *(const uint4*)(kcol);
        uint4 pk1 = *(const uint4*)(kcol + 8);
        uint4 pv0 = *(const uint4*)(vcol);
        uint4 pv1 = *(const uint4*)(vcol + 8);

        float l = 0.f;
        f32x4 o[4];
#pragma unroll
        for (int dt = 0; dt < 4; ++dt) o[dt] = f32x4{0.f, 0.f, 0.f, 0.f};

        for (int t = 0; t <= qt; ++t) {
            *(uint4*)(&Ks[pr * LDS_ + c0])     = pk0;
            *(uint4*)(&Ks[pr * LDS_ + c0 + 8]) = pk1;
            *(uint4*)(&Vs[kr * LDS_ + c0])     = pv0;
            *(uint4*)(&Vs[kr * LDS_ + c0 + 8]) = pv1;
            __syncthreads();
            if (t < qt) {                   // prefetch next tile, overlaps compute
                const bf16* kn = kcol + (size_t)(t + 1) * 64 * 2048;
                const bf16* vn = vcol + (t + 1) * 64;
                pk0 = *(const uint4*)(kn);
                pk1 = *(const uint4*)(kn + 8);
                pv0 = *(const uint4*)(vn);
                pv1 = *(const uint4*)(vn + 8);
            }

            // S^T = K Q^T : A-frag = permuted K rows, B-frag = qf
            f32x4 s[4];
#pragma unroll
            for (int mt = 0; mt < 4; ++mt) s[mt] = f32x4{0.f, 0.f, 0.f, 0.f};
#pragma unroll
            for (int mt = 0; mt < 4; ++mt) {
                bf16x8 a0 = *(const bf16x8*)(&Ks[(mt * 16 + l16) * LDS_ + lq * 8]);
                s[mt] = __builtin_amdgcn_mfma_f32_16x16x32_bf16(a0, qf0, s[mt], 0, 0, 0);
            }
#pragma unroll
            for (int mt = 0; mt < 4; ++mt) {
                bf16x8 a1 = *(const bf16x8*)(&Ks[(mt * 16 + l16) * LDS_ + 32 + lq * 8]);
                s[mt] = __builtin_amdgcn_mfma_f32_16x16x32_bf16(a1, qf1, s[mt], 0, 0, 0);
            }
            if (t == qt) {                  // causal mask, diagonal tile only
                const int qloc = wv * 16 + l16;
#pragma unroll
                for (int mt = 0; mt < 4; ++mt)
#pragma unroll
                    for (int r = 0; r < 4; ++r) {
                        int keyl = (mt >> 1) * 32 + lq * 8 + (mt & 1) * 4 + r;
                        if (keyl > qloc) s[mt][r] = -1e30f;
                    }
            }
            // exp2 + row-sum partials; pack C-regs directly into PV B-frags
            bf16x8 pb0, pb1;
#pragma unroll
            for (int mt = 0; mt < 4; ++mt)
#pragma unroll
                for (int r = 0; r < 4; ++r) {
                    float p = exp2f(s[mt][r]);
                    l += p;
                    s[mt][r] = p;
                }
#pragma unroll
            for (int r = 0; r < 4; ++r) {
                pb0[r]     = (bf16)s[0][r];
                pb0[4 + r] = (bf16)s[1][r];
                pb1[r]     = (bf16)s[2][r];
                pb1[4 + r] = (bf16)s[3][r];
            }
            // O^T += V^T P^T : A-frag = Vs rows (dims), B-frag = pb
#pragma unroll
            for (int dt = 0; dt < 4; ++dt) {
                bf16x8 v0 = *(const bf16x8*)(&Vs[(dt * 16 + l16) * LDS_ + lq * 8]);
                o[dt] = __builtin_amdgcn_mfma_f32_16x16x32_bf16(v0, pb0, o[dt], 0, 0, 0);
            }
#pragma unroll
            for (int dt = 0; dt < 4; ++dt) {
                bf16x8 v1 = *(const bf16x8*)(&Vs[(dt * 16 + l16) * LDS_ + 32 + lq * 8]);
                o[dt] = __builtin_amdgcn_mfma_f32_16x16x32_bf16(v1, pb1, o[dt], 0, 0, 0);
            }
            __syncthreads();                // all waves done with Ks/Vs tile t
        }
        // l per-lane for query l16; sum partials across lq (lane bits 4,5)
        l += __shfl_xor(l, 16);
        l += __shfl_xor(l, 32);
        float inv = 1.f / l;
        // O^T C-layout: d = dt*16 + lq*4 + r (register-contiguous) -> bf16x4
        bf16* op = O + (size_t)(b * Tt + qglob) * Cc + h * 64;
#pragma unroll
        for (int dt = 0; dt < 4; ++dt) {
            bf16x4 pk;
#pragma unroll
            for (int r = 0; r < 4; ++r) pk[r] = (bf16)(o[dt][r] * inv);
            *(bf16x4*)(op + dt * 16 + lq * 4) = pk;
        }
        // epilogue is register/global only; loop's final __syncthreads()
        // already guards LDS reuse by the next phase's commits
    }
}

extern "C" void kernel_launch(void* const* d_in, const int* in_sizes, int n_in,
                              void* d_out, int out_size, void* d_ws, size_t ws_size,
                              hipStream_t stream)
{
    const float* x    = (const float*)d_in[0];
    const float* Wq   = (const float*)d_in[1];
    const float* Wk   = (const float*)d_in[2];
    const float* Wv   = (const float*)d_in[3];
    const float* Wo   = (const float*)d_in[4];
    const float* cosb = (const float*)d_in[5];
    const float* sinb = (const float*)d_in[6];

    constexpr size_t M1 = 1024 * 1024;
    bf16* base = (bf16*)d_ws;
    bf16*   xb   = base;                    //  0..4M   (reused as attn out)
    bf16*   QK   = base + 4 * M1;           //  4M..12M [4096][2048]
    bf16*   VtG  = base + 12 * M1;          // 12M..16M [32][64][2048]
    bf16*   Wqkv = base + 16 * M1;          // 16M..19M [3072][1024]
    bf16*   Wob  = base + 19 * M1;          // 19M..20M
    float2* csT  = (float2*)(base + 20 * M1); // 512 KB
    bf16*   Ow   = xb;

    convert_k<<<4096 + 32, 256, 0, stream>>>(x, Wq, Wk, Wv, Wo, cosb, sinb,
                                             xb, Wqkv, Wob, csT);

    gemm_qkv<<<dim3(Mrows / BM, 3072 / BN), 256, 0, stream>>>(
        xb, Wqkv, QK, VtG, csT);

    attn_k<<<dim3(NT / 2, Bb * Hh), 256, 0, stream>>>(QK, VtG, Ow);

    gemm_o<<<dim3(Mrows / BM, Cc / 64), 256, 0, stream>>>(Ow, Wob, (float*)d_out);
}

// Round 10
// 174.570 us; speedup vs baseline: 1.2144x; 1.1638x over previous
//
#include <hip/hip_runtime.h>
#include <cstdint>
#include <cstddef>

// ---------------------------------------------------------------------------
// Fused causal attention block: QKV proj (+RoPE) -> MFMA flash attn -> out proj
// B=2 T=2048 C=1024 H=16 HD=64. Inputs fp32, output fp32, internal bf16 MFMA.
// R10: GEMM inputs stored in SWIZZLED fragment-order tiles to kill the 9.4e6
// LDS bank conflicts (row stride 128B = 32 banks made every ds_read_b128
// 16-lane same-bank). Tile (128x64) = 1024 chunks of 16B ordered
// [rowhalf][ks][i][lq][l16]: staging = contiguous 1KB wave segments via
// global_load_lds; fragment reads = 64 consecutive lane-linear slots -> zero
// conflicts. Producers emit the layout: convert_k (xb, Wqkv, Wob[64-row
// tiles]) and attn epilogue (O -> swizzled for gemm_o's A side).
// ws (bf16 elems): xb@0 (4M, reused as swizzled attn-out), QK@4M (8M, stride
// 2048), Vt@12M (4M), Wqkv@16M (3M), Wob@19M (1M), cs-table@20M (512KB).
// ---------------------------------------------------------------------------

typedef __bf16 bf16;
typedef float  f32x4  __attribute__((ext_vector_type(4)));
typedef __bf16 bf16x4 __attribute__((ext_vector_type(4)));
typedef __bf16 bf16x8 __attribute__((ext_vector_type(8)));

constexpr int Bb = 2, Tt = 2048, Cc = 1024, Hh = 16;
constexpr int Mrows = Bb * Tt;          // 4096
constexpr int NT = Tt / 64;             // 32 key/query tiles
constexpr int LDS_ = 72;                // attention LDS stride

#define GLOAD_LDS16(gp, lp)                                                      \
    __builtin_amdgcn_global_load_lds(                                            \
        (const __attribute__((address_space(1))) void*)(gp),                     \
        (__attribute__((address_space(3))) void*)(lp), 16, 0, 0)

// 4x4 transpose across lanes (low 2 bits of l16) x regs
#define QUAD_T(v0, v1, v2, v3, c2)                                               \
    {                                                                            \
        float e0 = (c2 & 1) ? v0 : v1, e1 = (c2 & 1) ? v2 : v3;                  \
        e0 = __shfl_xor(e0, 1); e1 = __shfl_xor(e1, 1);                          \
        if (c2 & 1) { v0 = e0; v2 = e1; } else { v1 = e0; v3 = e1; }             \
        float f0 = (c2 & 2) ? v0 : v2, f1 = (c2 & 2) ? v1 : v3;                  \
        f0 = __shfl_xor(f0, 2); f1 = __shfl_xor(f1, 2);                          \
        if (c2 & 2) { v0 = f0; v1 = f1; } else { v2 = f0; v3 = f1; }             \
    }

// ---- convert: fp32 -> bf16 into swizzled tiles; Wq pre-scaled; cs packing ----
// 128-row tile (1024 chunks): slot = rh*512 + ks*256 + i*64 + lq*16 + l16
//   row' = rh*64 + i*16 + l16 ; k' = ks*32 + lq*8
// 64-row tile (512 chunks):   slot = ch*256 + ks*128 + j*64 + lq*16 + l16
__global__ __launch_bounds__(256) void convert_k(const float* __restrict__ x,
                                                 const float* __restrict__ Wq,
                                                 const float* __restrict__ Wk,
                                                 const float* __restrict__ Wv,
                                                 const float* __restrict__ Wo,
                                                 const float* __restrict__ cosb,
                                                 const float* __restrict__ sinb,
                                                 bf16* __restrict__ xb,
                                                 bf16* __restrict__ Wqkv,
                                                 bf16* __restrict__ Wob,
                                                 float2* __restrict__ cs)
{
    if (blockIdx.x >= 4096) {           // cs-table packing: 65536 (t,p) pairs
        int pi = ((blockIdx.x - 4096) * 256 + threadIdx.x) * 8;
#pragma unroll
        for (int u = 0; u < 8; ++u)
            cs[pi + u] = float2{cosb[pi + u], sinb[pi + u]};
        return;
    }
    uint32_t id = blockIdx.x * 256 + threadIdx.x;      // one 16-B dst chunk
    const float* src; bf16* dst; float sc = 1.0f;
    if (id < 524288u) {                                // xb: 32rb x 16kb x 1024
        uint32_t tile = id >> 10, slot = id & 1023;
        uint32_t row = (tile >> 4) * 128 + (slot >> 9) * 64 +
                       ((slot >> 6) & 3) * 16 + (slot & 15);
        uint32_t k = (tile & 15) * 64 + ((slot >> 8) & 1) * 32 + ((slot >> 4) & 3) * 8;
        src = x + (size_t)row * 1024 + k;
        dst = xb + (size_t)id * 8;
    } else if (id < 917504u) {                         // Wqkv: 24cb x 16kb x 1024
        uint32_t t2 = id - 524288u;
        uint32_t tile = t2 >> 10, slot = t2 & 1023;
        uint32_t n = (tile >> 4) * 128 + (slot >> 9) * 64 +
                     ((slot >> 6) & 3) * 16 + (slot & 15);
        uint32_t k = (tile & 15) * 64 + ((slot >> 8) & 1) * 32 + ((slot >> 4) & 3) * 8;
        if (n < 1024)      { src = Wq + (size_t)n * 1024 + k;
                             sc = 0.125f * 1.44269504088896f; }
        else if (n < 2048)   src = Wk + (size_t)(n - 1024) * 1024 + k;
        else                 src = Wv + (size_t)(n - 2048) * 1024 + k;
        dst = Wqkv + (size_t)t2 * 8;
    } else {                                           // Wob: 16cb x 16kb x 512
        uint32_t t3 = id - 917504u;
        uint32_t tile = t3 >> 9, slot = t3 & 511;
        uint32_t n = (tile >> 4) * 64 + (slot >> 8) * 32 +
                     ((slot >> 6) & 1) * 16 + (slot & 15);
        uint32_t k = (tile & 15) * 64 + ((slot >> 7) & 1) * 32 + ((slot >> 4) & 3) * 8;
        src = Wo + (size_t)n * 1024 + k;
        dst = Wob + (size_t)t3 * 8;
    }
    float4 v0 = *(const float4*)(src);
    float4 v1 = *(const float4*)(src + 4);
    bf16x8 t;
    t[0] = (bf16)(v0.x*sc); t[1] = (bf16)(v0.y*sc); t[2] = (bf16)(v0.z*sc); t[3] = (bf16)(v0.w*sc);
    t[4] = (bf16)(v1.x*sc); t[5] = (bf16)(v1.y*sc); t[6] = (bf16)(v1.z*sc); t[7] = (bf16)(v1.w*sc);
    *(bf16x8*)dst = t;
}

// ---- QKV GEMM [4096x3072x1024], swizzled-tile inputs, RoPE/Vt epilogue ----
__global__ __launch_bounds__(256) void gemm_qkv(const bf16* __restrict__ A,
                                                const bf16* __restrict__ W,
                                                bf16* __restrict__ QK,
                                                bf16* __restrict__ Vt,
                                                const float2* __restrict__ cs)
{
    __shared__ bf16 As[8192];
    __shared__ bf16 Ws[8192];
    const int tid  = threadIdx.x;
    const int lane = tid & 63, wave = tid >> 6;
    const int rhw = wave >> 1, chw = wave & 1;
    const int wr = rhw * 64, wc = chw * 64;
    const int l16 = lane & 15, lq = lane >> 4;
    const int row0 = blockIdx.x * 128, col0 = blockIdx.y * 128;

    f32x4 acc[4][4];
#pragma unroll
    for (int i = 0; i < 4; ++i)
#pragma unroll
        for (int j = 0; j < 4; ++j) acc[i][j] = f32x4{0.f, 0.f, 0.f, 0.f};

    const bf16* At = A + (size_t)blockIdx.x * 16 * 8192;
    const bf16* Wt = W + (size_t)blockIdx.y * 16 * 8192;

    for (int kb = 0; kb < 16; ++kb) {
        const bf16* at = At + kb * 8192;
        const bf16* wt = Wt + kb * 8192;
#pragma unroll
        for (int rnd = 0; rnd < 4; ++rnd) {
            const int seg = rnd * 4 + wave;            // contiguous 1KB segment
            GLOAD_LDS16(at + seg * 512 + lane * 8, &As[seg * 512]);
            GLOAD_LDS16(wt + seg * 512 + lane * 8, &Ws[seg * 512]);
        }
        __syncthreads();
#pragma unroll
        for (int ks = 0; ks < 2; ++ks) {
            bf16x8 af[4], bfr[4];
#pragma unroll
            for (int i = 0; i < 4; ++i)
                af[i] = *(const bf16x8*)(&As[(rhw * 512 + ks * 256 + i * 64 + lq * 16 + l16) * 8]);
#pragma unroll
            for (int j = 0; j < 4; ++j)
                bfr[j] = *(const bf16x8*)(&Ws[(chw * 512 + ks * 256 + j * 64 + lq * 16 + l16) * 8]);
#pragma unroll
            for (int i = 0; i < 4; ++i)
#pragma unroll
                for (int j = 0; j < 4; ++j)
                    acc[i][j] = __builtin_amdgcn_mfma_f32_16x16x32_bf16(
                        af[i], bfr[j], acc[i][j], 0, 0, 0);
        }
        __syncthreads();
    }

    const int c2 = l16 & 3, g4 = (l16 >> 2) * 4;
    if (blockIdx.y < 16) {
        // Q/K tile: quad-transpose -> lane owns 1 row x 4 cols; RoPE intra-lane
#pragma unroll
        for (int i = 0; i < 4; ++i)
#pragma unroll
            for (int j = 0; j < 4; ++j) {
                float v0 = acc[i][j][0], v1 = acc[i][j][1];
                float v2 = acc[i][j][2], v3 = acc[i][j][3];
                QUAD_T(v0, v1, v2, v3, c2);
                const int row = row0 + wr + i * 16 + lq * 4 + c2;
                const int t   = row & (Tt - 1);
                const int colb = wc + j * 16 + g4;
                const int p0   = (colb & 63) >> 1;
                float4 cp = *(const float4*)(&cs[t * 32 + p0]);  // (c0,s0,c1,s1)
                bf16x4 pk;
                pk[0] = (bf16)(v0 * cp.x - v1 * cp.y);
                pk[1] = (bf16)(v0 * cp.y + v1 * cp.x);
                pk[2] = (bf16)(v2 * cp.z - v3 * cp.w);
                pk[3] = (bf16)(v2 * cp.w + v3 * cp.z);
                *(bf16x4*)(&QK[(size_t)row * 2048 + col0 + colb]) = pk;
            }
    } else {
        // V tile: transposed store into Vt[bh][d][t]
#pragma unroll
        for (int i = 0; i < 4; ++i)
#pragma unroll
            for (int j = 0; j < 4; ++j) {
                const int dfull = col0 - 2048 + wc + j * 16 + l16;
                const int h = dfull >> 6, d = dfull & 63;
                const int row = row0 + wr + i * 16 + lq * 4;
                const int b = row >> 11, t = row & (Tt - 1);
                bf16x4 pk;
                pk[0] = (bf16)acc[i][j][0]; pk[1] = (bf16)acc[i][j][1];
                pk[2] = (bf16)acc[i][j][2]; pk[3] = (bf16)acc[i][j][3];
                *(bf16x4*)(&Vt[((size_t)(b * 16 + h) * 64 + d) * (size_t)Tt + t]) = pk;
            }
    }
}

// ---- O GEMM: 128x64 tiles, swizzled A (from attn) + swizzled Wob, fp32 out --
__global__ __launch_bounds__(256) void gemm_o(const bf16* __restrict__ A,
                                              const bf16* __restrict__ W,
                                              float* __restrict__ Out)
{
    __shared__ bf16 As[8192];
    __shared__ bf16 Ws[4096];
    const int tid  = threadIdx.x;
    const int lane = tid & 63, wave = tid >> 6;
    const int rhw = wave >> 1, chw = wave & 1;
    const int wr = rhw * 64, wc = chw * 32;
    const int l16 = lane & 15, lq = lane >> 4;
    const int row0 = blockIdx.x * 128, col0 = blockIdx.y * 64;

    f32x4 acc[4][2];
#pragma unroll
    for (int i = 0; i < 4; ++i)
#pragma unroll
        for (int j = 0; j < 2; ++j) acc[i][j] = f32x4{0.f, 0.f, 0.f, 0.f};

    const bf16* At = A + (size_t)blockIdx.x * 16 * 8192;
    const bf16* Wt = W + (size_t)blockIdx.y * 16 * 4096;

    for (int kb = 0; kb < 16; ++kb) {
        const bf16* at = At + kb * 8192;
        const bf16* wt = Wt + kb * 4096;
#pragma unroll
        for (int rnd = 0; rnd < 4; ++rnd) {
            const int seg = rnd * 4 + wave;
            GLOAD_LDS16(at + seg * 512 + lane * 8, &As[seg * 512]);
        }
#pragma unroll
        for (int rnd = 0; rnd < 2; ++rnd) {
            const int seg = rnd * 4 + wave;
            GLOAD_LDS16(wt + seg * 512 + lane * 8, &Ws[seg * 512]);
        }
        __syncthreads();
#pragma unroll
        for (int ks = 0; ks < 2; ++ks) {
            bf16x8 af[4], bfr[2];
#pragma unroll
            for (int i = 0; i < 4; ++i)
                af[i] = *(const bf16x8*)(&As[(rhw * 512 + ks * 256 + i * 64 + lq * 16 + l16) * 8]);
#pragma unroll
            for (int j = 0; j < 2; ++j)
                bfr[j] = *(const bf16x8*)(&Ws[(chw * 256 + ks * 128 + j * 64 + lq * 16 + l16) * 8]);
#pragma unroll
            for (int i = 0; i < 4; ++i)
#pragma unroll
                for (int j = 0; j < 2; ++j)
                    acc[i][j] = __builtin_amdgcn_mfma_f32_16x16x32_bf16(
                        af[i], bfr[j], acc[i][j], 0, 0, 0);
        }
        __syncthreads();
    }
    const int c2 = l16 & 3, g4 = (l16 >> 2) * 4;
#pragma unroll
    for (int i = 0; i < 4; ++i)
#pragma unroll
        for (int j = 0; j < 2; ++j) {
            float v0 = acc[i][j][0], v1 = acc[i][j][1];
            float v2 = acc[i][j][2], v3 = acc[i][j][3];
            QUAD_T(v0, v1, v2, v3, c2);
            const int row = row0 + wr + i * 16 + lq * 4 + c2;
            const int col = col0 + wc + j * 16 + g4;
            *(float4*)(&Out[(size_t)row * Cc + col]) = float4{v0, v1, v2, v3};
        }
}

// ---- MFMA flash attention (S^T form), causal, static-max, reg dbuf, PAIRED.
// O stored directly in gemm_o's swizzled A-tile layout.
__global__ __launch_bounds__(256, 4) void attn_k(const bf16* __restrict__ QK,
                                                 const bf16* __restrict__ Vt,
                                                 bf16* __restrict__ O)
{
    __shared__ bf16 Ks[64 * LDS_];
    __shared__ bf16 Vs[64 * LDS_];
    const int tid = threadIdx.x;
    const int wv = tid >> 6, lane = tid & 63;
    const int l16 = lane & 15, lq = lane >> 4;
    const int bh = blockIdx.y, b = bh >> 4, h = bh & 15;
    const int kr = tid >> 2, c0 = (tid & 3) * 16;       // staging coords
    // permuted LDS row: key -> 32*(k>>5) + 16*((k>>2)&1) + 4*((k>>3)&3) + (k&3)
    const int pr = 32 * (kr >> 5) + 16 * ((kr >> 2) & 1) + 4 * ((kr >> 3) & 3) + (kr & 3);

    const bf16* kcol = QK + 1024 + (size_t)(b * Tt + kr) * 2048 + h * 64 + c0;
    const bf16* vcol = Vt + ((size_t)bh * 64 + kr) * Tt + c0;

    for (int phase = 0; phase < 2; ++phase) {
        const int qt = phase ? blockIdx.x : (NT - 1 - blockIdx.x);

        // Q B-fragments straight from global (Q pre-scaled by 0.125*log2e)
        const int qglob = qt * 64 + wv * 16 + l16;
        const bf16* qp = QK + (size_t)(b * Tt + qglob) * 2048 + h * 64;
        bf16x8 qf0 = *(const bf16x8*)(qp + lq * 8);
        bf16x8 qf1 = *(const bf16x8*)(qp + 32 + lq * 8);

        uint4 pk0 = *(const uint4*)(kcol);
        uint4 pk1 = *(const uint4*)(kcol + 8);
        uint4 pv0 = *(const uint4*)(vcol);
        uint4 pv1 = *(const uint4*)(vcol + 8);

        float l = 0.f;
        f32x4 o[4];
#pragma unroll
        for (int dt = 0; dt < 4; ++dt) o[dt] = f32x4{0.f, 0.f, 0.f, 0.f};

        for (int t = 0; t <= qt; ++t) {
            *(uint4*)(&Ks[pr * LDS_ + c0])     = pk0;
            *(uint4*)(&Ks[pr * LDS_ + c0 + 8]) = pk1;
            *(uint4*)(&Vs[kr * LDS_ + c0])     = pv0;
            *(uint4*)(&Vs[kr * LDS_ + c0 + 8]) = pv1;
            __syncthreads();
            if (t < qt) {                   // prefetch next tile, overlaps compute
                const bf16* kn = kcol + (size_t)(t + 1) * 64 * 2048;
                const bf16* vn = vcol + (t + 1) * 64;
                pk0 = *(const uint4*)(kn);
                pk1 = *(const uint4*)(kn + 8);
                pv0 = *(const uint4*)(vn);
                pv1 = *(const uint4*)(vn + 8);
            }

            // S^T = K Q^T : A-frag = permuted K rows, B-frag = qf
            f32x4 s[4];
#pragma unroll
            for (int mt = 0; mt < 4; ++mt) s[mt] = f32x4{0.f, 0.f, 0.f, 0.f};
#pragma unroll
            for (int mt = 0; mt < 4; ++mt) {
                bf16x8 a0 = *(const bf16x8*)(&Ks[(mt * 16 + l16) * LDS_ + lq * 8]);
                s[mt] = __builtin_amdgcn_mfma_f32_16x16x32_bf16(a0, qf0, s[mt], 0, 0, 0);
            }
#pragma unroll
            for (int mt = 0; mt < 4; ++mt) {
                bf16x8 a1 = *(const bf16x8*)(&Ks[(mt * 16 + l16) * LDS_ + 32 + lq * 8]);
                s[mt] = __builtin_amdgcn_mfma_f32_16x16x32_bf16(a1, qf1, s[mt], 0, 0, 0);
            }
            if (t == qt) {                  // causal mask, diagonal tile only
                const int qloc = wv * 16 + l16;
#pragma unroll
                for (int mt = 0; mt < 4; ++mt)
#pragma unroll
                    for (int r = 0; r < 4; ++r) {
                        int keyl = (mt >> 1) * 32 + lq * 8 + (mt & 1) * 4 + r;
                        if (keyl > qloc) s[mt][r] = -1e30f;
                    }
            }
            // exp2 + sum partials; C-regs become PV B-frags directly
            bf16x8 pb0, pb1;
#pragma unroll
            for (int mt = 0; mt < 4; ++mt)
#pragma unroll
                for (int r = 0; r < 4; ++r) {
                    float p = exp2f(s[mt][r]);
                    l += p;
                    s[mt][r] = p;
                }
#pragma unroll
            for (int r = 0; r < 4; ++r) {
                pb0[r]     = (bf16)s[0][r];
                pb0[4 + r] = (bf16)s[1][r];
                pb1[r]     = (bf16)s[2][r];
                pb1[4 + r] = (bf16)s[3][r];
            }
            // O^T += V^T P^T
#pragma unroll
            for (int dt = 0; dt < 4; ++dt) {
                bf16x8 v0 = *(const bf16x8*)(&Vs[(dt * 16 + l16) * LDS_ + lq * 8]);
                o[dt] = __builtin_amdgcn_mfma_f32_16x16x32_bf16(v0, pb0, o[dt], 0, 0, 0);
            }
#pragma unroll
            for (int dt = 0; dt < 4; ++dt) {
                bf16x8 v1 = *(const bf16x8*)(&Vs[(dt * 16 + l16) * LDS_ + 32 + lq * 8]);
                o[dt] = __builtin_amdgcn_mfma_f32_16x16x32_bf16(v1, pb1, o[dt], 0, 0, 0);
            }
            __syncthreads();                // all waves done with Ks/Vs tile t
        }
        // softmax denom: sum partials across lq (lane bits 4,5)
        l += __shfl_xor(l, 16);
        l += __shfl_xor(l, 32);
        float inv = 1.f / l;
        // store O in gemm_o's swizzled A layout:
        // tile = (b*16 + qt/2)*16 + h ; slot = (qt&1)*512 + (dt>>1)*256 + wv*64
        //        + ((dt&1)*2 + (lq>>1))*16 + l16 ; byte-half = lq&1
        bf16* obase = O + ((size_t)(b * 16 + (qt >> 1)) * 16 + h) * 8192;
        const int rh = qt & 1;
#pragma unroll
        for (int dt = 0; dt < 4; ++dt) {
            bf16x4 pk;
#pragma unroll
            for (int r = 0; r < 4; ++r) pk[r] = (bf16)(o[dt][r] * inv);
            const int slot = rh * 512 + (dt >> 1) * 256 + wv * 64 +
                             ((dt & 1) * 2 + (lq >> 1)) * 16 + l16;
            *(bf16x4*)(obase + slot * 8 + (lq & 1) * 4) = pk;
        }
    }
}

extern "C" void kernel_launch(void* const* d_in, const int* in_sizes, int n_in,
                              void* d_out, int out_size, void* d_ws, size_t ws_size,
                              hipStream_t stream)
{
    const float* x    = (const float*)d_in[0];
    const float* Wq   = (const float*)d_in[1];
    const float* Wk   = (const float*)d_in[2];
    const float* Wv   = (const float*)d_in[3];
    const float* Wo   = (const float*)d_in[4];
    const float* cosb = (const float*)d_in[5];
    const float* sinb = (const float*)d_in[6];

    constexpr size_t M1 = 1024 * 1024;
    bf16* base = (bf16*)d_ws;
    bf16*   xb   = base;                    //  0..4M   swizzled x; reused attn-out
    bf16*   QK   = base + 4 * M1;           //  4M..12M [4096][2048]
    bf16*   VtG  = base + 12 * M1;          // 12M..16M [32][64][2048]
    bf16*   Wqkv = base + 16 * M1;          // 16M..19M swizzled
    bf16*   Wob  = base + 19 * M1;          // 19M..20M swizzled (64-row tiles)
    float2* csT  = (float2*)(base + 20 * M1); // 512 KB
    bf16*   Ow   = xb;

    convert_k<<<4096 + 32, 256, 0, stream>>>(x, Wq, Wk, Wv, Wo, cosb, sinb,
                                             xb, Wqkv, Wob, csT);

    gemm_qkv<<<dim3(Mrows / 128, 3072 / 128), 256, 0, stream>>>(
        xb, Wqkv, QK, VtG, csT);

    attn_k<<<dim3(NT / 2, Bb * Hh), 256, 0, stream>>>(QK, VtG, Ow);

    gemm_o<<<dim3(Mrows / 128, Cc / 64), 256, 0, stream>>>(Ow, Wob, (float*)d_out);
}

// Round 11
// 172.529 us; speedup vs baseline: 1.2288x; 1.0118x over previous
//
#include <hip/hip_runtime.h>
#include <cstdint>
#include <cstddef>

// ---------------------------------------------------------------------------
// Fused causal attention block: QKV proj (+RoPE) -> MFMA flash attn -> out proj
// B=2 T=2048 C=1024 H=16 HD=64. Inputs fp32, output fp32, internal bf16 MFMA.
// R11: attn double-buffered LDS (1 barrier/step, was 2; store of t+1 moved
// after compute of t) + XCD-aware block swizzle (all 16 blocks sharing a
// (b,h)'s K/V on one XCD: bh=(id&7)*4+(id>>7) -- R10 FETCH 94.5MB was 8x
// L2 replication of K/V across XCDs). Rest identical to R10 (swizzled GEMM
// tiles, S^T attn with P-in-registers, paired q-tiles, fused RoPE/Vt).
// Known floor in dur_us: harness 0xAA ws-poison fill ~43us + ~10us gaps.
// ws (bf16 elems): xb@0 (4M, reused as swizzled attn-out), QK@4M (8M, stride
// 2048), Vt@12M (4M), Wqkv@16M (3M), Wob@19M (1M), cs-table@20M (512KB).
// ---------------------------------------------------------------------------

typedef __bf16 bf16;
typedef float  f32x4  __attribute__((ext_vector_type(4)));
typedef __bf16 bf16x4 __attribute__((ext_vector_type(4)));
typedef __bf16 bf16x8 __attribute__((ext_vector_type(8)));

constexpr int Bb = 2, Tt = 2048, Cc = 1024, Hh = 16;
constexpr int Mrows = Bb * Tt;          // 4096
constexpr int NT = Tt / 64;             // 32 key/query tiles
constexpr int LDS_ = 72;                // attention LDS stride

#define GLOAD_LDS16(gp, lp)                                                      \
    __builtin_amdgcn_global_load_lds(                                            \
        (const __attribute__((address_space(1))) void*)(gp),                     \
        (__attribute__((address_space(3))) void*)(lp), 16, 0, 0)

// 4x4 transpose across lanes (low 2 bits of l16) x regs
#define QUAD_T(v0, v1, v2, v3, c2)                                               \
    {                                                                            \
        float e0 = (c2 & 1) ? v0 : v1, e1 = (c2 & 1) ? v2 : v3;                  \
        e0 = __shfl_xor(e0, 1); e1 = __shfl_xor(e1, 1);                          \
        if (c2 & 1) { v0 = e0; v2 = e1; } else { v1 = e0; v3 = e1; }             \
        float f0 = (c2 & 2) ? v0 : v2, f1 = (c2 & 2) ? v1 : v3;                  \
        f0 = __shfl_xor(f0, 2); f1 = __shfl_xor(f1, 2);                          \
        if (c2 & 2) { v0 = f0; v1 = f1; } else { v2 = f0; v3 = f1; }             \
    }

// ---- convert: fp32 -> bf16 into swizzled tiles; Wq pre-scaled; cs packing ----
__global__ __launch_bounds__(256) void convert_k(const float* __restrict__ x,
                                                 const float* __restrict__ Wq,
                                                 const float* __restrict__ Wk,
                                                 const float* __restrict__ Wv,
                                                 const float* __restrict__ Wo,
                                                 const float* __restrict__ cosb,
                                                 const float* __restrict__ sinb,
                                                 bf16* __restrict__ xb,
                                                 bf16* __restrict__ Wqkv,
                                                 bf16* __restrict__ Wob,
                                                 float2* __restrict__ cs)
{
    if (blockIdx.x >= 4096) {           // cs-table packing: 65536 (t,p) pairs
        int pi = ((blockIdx.x - 4096) * 256 + threadIdx.x) * 8;
#pragma unroll
        for (int u = 0; u < 8; ++u)
            cs[pi + u] = float2{cosb[pi + u], sinb[pi + u]};
        return;
    }
    uint32_t id = blockIdx.x * 256 + threadIdx.x;      // one 16-B dst chunk
    const float* src; bf16* dst; float sc = 1.0f;
    if (id < 524288u) {                                // xb: 32rb x 16kb x 1024
        uint32_t tile = id >> 10, slot = id & 1023;
        uint32_t row = (tile >> 4) * 128 + (slot >> 9) * 64 +
                       ((slot >> 6) & 3) * 16 + (slot & 15);
        uint32_t k = (tile & 15) * 64 + ((slot >> 8) & 1) * 32 + ((slot >> 4) & 3) * 8;
        src = x + (size_t)row * 1024 + k;
        dst = xb + (size_t)id * 8;
    } else if (id < 917504u) {                         // Wqkv: 24cb x 16kb x 1024
        uint32_t t2 = id - 524288u;
        uint32_t tile = t2 >> 10, slot = t2 & 1023;
        uint32_t n = (tile >> 4) * 128 + (slot >> 9) * 64 +
                     ((slot >> 6) & 3) * 16 + (slot & 15);
        uint32_t k = (tile & 15) * 64 + ((slot >> 8) & 1) * 32 + ((slot >> 4) & 3) * 8;
        if (n < 1024)      { src = Wq + (size_t)n * 1024 + k;
                             sc = 0.125f * 1.44269504088896f; }
        else if (n < 2048)   src = Wk + (size_t)(n - 1024) * 1024 + k;
        else                 src = Wv + (size_t)(n - 2048) * 1024 + k;
        dst = Wqkv + (size_t)t2 * 8;
    } else {                                           // Wob: 16cb x 16kb x 512
        uint32_t t3 = id - 917504u;
        uint32_t tile = t3 >> 9, slot = t3 & 511;
        uint32_t n = (tile >> 4) * 64 + (slot >> 8) * 32 +
                     ((slot >> 6) & 1) * 16 + (slot & 15);
        uint32_t k = (tile & 15) * 64 + ((slot >> 7) & 1) * 32 + ((slot >> 4) & 3) * 8;
        src = Wo + (size_t)n * 1024 + k;
        dst = Wob + (size_t)t3 * 8;
    }
    float4 v0 = *(const float4*)(src);
    float4 v1 = *(const float4*)(src + 4);
    bf16x8 t;
    t[0] = (bf16)(v0.x*sc); t[1] = (bf16)(v0.y*sc); t[2] = (bf16)(v0.z*sc); t[3] = (bf16)(v0.w*sc);
    t[4] = (bf16)(v1.x*sc); t[5] = (bf16)(v1.y*sc); t[6] = (bf16)(v1.z*sc); t[7] = (bf16)(v1.w*sc);
    *(bf16x8*)dst = t;
}

// ---- QKV GEMM [4096x3072x1024], swizzled-tile inputs, RoPE/Vt epilogue ----
__global__ __launch_bounds__(256) void gemm_qkv(const bf16* __restrict__ A,
                                                const bf16* __restrict__ W,
                                                bf16* __restrict__ QK,
                                                bf16* __restrict__ Vt,
                                                const float2* __restrict__ cs)
{
    __shared__ bf16 As[8192];
    __shared__ bf16 Ws[8192];
    const int tid  = threadIdx.x;
    const int lane = tid & 63, wave = tid >> 6;
    const int rhw = wave >> 1, chw = wave & 1;
    const int wr = rhw * 64, wc = chw * 64;
    const int l16 = lane & 15, lq = lane >> 4;
    const int row0 = blockIdx.x * 128, col0 = blockIdx.y * 128;

    f32x4 acc[4][4];
#pragma unroll
    for (int i = 0; i < 4; ++i)
#pragma unroll
        for (int j = 0; j < 4; ++j) acc[i][j] = f32x4{0.f, 0.f, 0.f, 0.f};

    const bf16* At = A + (size_t)blockIdx.x * 16 * 8192;
    const bf16* Wt = W + (size_t)blockIdx.y * 16 * 8192;

    for (int kb = 0; kb < 16; ++kb) {
        const bf16* at = At + kb * 8192;
        const bf16* wt = Wt + kb * 8192;
#pragma unroll
        for (int rnd = 0; rnd < 4; ++rnd) {
            const int seg = rnd * 4 + wave;            // contiguous 1KB segment
            GLOAD_LDS16(at + seg * 512 + lane * 8, &As[seg * 512]);
            GLOAD_LDS16(wt + seg * 512 + lane * 8, &Ws[seg * 512]);
        }
        __syncthreads();
#pragma unroll
        for (int ks = 0; ks < 2; ++ks) {
            bf16x8 af[4], bfr[4];
#pragma unroll
            for (int i = 0; i < 4; ++i)
                af[i] = *(const bf16x8*)(&As[(rhw * 512 + ks * 256 + i * 64 + lq * 16 + l16) * 8]);
#pragma unroll
            for (int j = 0; j < 4; ++j)
                bfr[j] = *(const bf16x8*)(&Ws[(chw * 512 + ks * 256 + j * 64 + lq * 16 + l16) * 8]);
#pragma unroll
            for (int i = 0; i < 4; ++i)
#pragma unroll
                for (int j = 0; j < 4; ++j)
                    acc[i][j] = __builtin_amdgcn_mfma_f32_16x16x32_bf16(
                        af[i], bfr[j], acc[i][j], 0, 0, 0);
        }
        __syncthreads();
    }

    const int c2 = l16 & 3, g4 = (l16 >> 2) * 4;
    if (blockIdx.y < 16) {
        // Q/K tile: quad-transpose -> lane owns 1 row x 4 cols; RoPE intra-lane
#pragma unroll
        for (int i = 0; i < 4; ++i)
#pragma unroll
            for (int j = 0; j < 4; ++j) {
                float v0 = acc[i][j][0], v1 = acc[i][j][1];
                float v2 = acc[i][j][2], v3 = acc[i][j][3];
                QUAD_T(v0, v1, v2, v3, c2);
                const int row = row0 + wr + i * 16 + lq * 4 + c2;
                const int t   = row & (Tt - 1);
                const int colb = wc + j * 16 + g4;
                const int p0   = (colb & 63) >> 1;
                float4 cp = *(const float4*)(&cs[t * 32 + p0]);  // (c0,s0,c1,s1)
                bf16x4 pk;
                pk[0] = (bf16)(v0 * cp.x - v1 * cp.y);
                pk[1] = (bf16)(v0 * cp.y + v1 * cp.x);
                pk[2] = (bf16)(v2 * cp.z - v3 * cp.w);
                pk[3] = (bf16)(v2 * cp.w + v3 * cp.z);
                *(bf16x4*)(&QK[(size_t)row * 2048 + col0 + colb]) = pk;
            }
    } else {
        // V tile: transposed store into Vt[bh][d][t]
#pragma unroll
        for (int i = 0; i < 4; ++i)
#pragma unroll
            for (int j = 0; j < 4; ++j) {
                const int dfull = col0 - 2048 + wc + j * 16 + l16;
                const int h = dfull >> 6, d = dfull & 63;
                const int row = row0 + wr + i * 16 + lq * 4;
                const int b = row >> 11, t = row & (Tt - 1);
                bf16x4 pk;
                pk[0] = (bf16)acc[i][j][0]; pk[1] = (bf16)acc[i][j][1];
                pk[2] = (bf16)acc[i][j][2]; pk[3] = (bf16)acc[i][j][3];
                *(bf16x4*)(&Vt[((size_t)(b * 16 + h) * 64 + d) * (size_t)Tt + t]) = pk;
            }
    }
}

// ---- O GEMM: 128x64 tiles, swizzled A (from attn) + swizzled Wob, fp32 out --
__global__ __launch_bounds__(256) void gemm_o(const bf16* __restrict__ A,
                                              const bf16* __restrict__ W,
                                              float* __restrict__ Out)
{
    __shared__ bf16 As[8192];
    __shared__ bf16 Ws[4096];
    const int tid  = threadIdx.x;
    const int lane = tid & 63, wave = tid >> 6;
    const int rhw = wave >> 1, chw = wave & 1;
    const int wr = rhw * 64, wc = chw * 32;
    const int l16 = lane & 15, lq = lane >> 4;
    const int row0 = blockIdx.x * 128, col0 = blockIdx.y * 64;

    f32x4 acc[4][2];
#pragma unroll
    for (int i = 0; i < 4; ++i)
#pragma unroll
        for (int j = 0; j < 2; ++j) acc[i][j] = f32x4{0.f, 0.f, 0.f, 0.f};

    const bf16* At = A + (size_t)blockIdx.x * 16 * 8192;
    const bf16* Wt = W + (size_t)blockIdx.y * 16 * 4096;

    for (int kb = 0; kb < 16; ++kb) {
        const bf16* at = At + kb * 8192;
        const bf16* wt = Wt + kb * 4096;
#pragma unroll
        for (int rnd = 0; rnd < 4; ++rnd) {
            const int seg = rnd * 4 + wave;
            GLOAD_LDS16(at + seg * 512 + lane * 8, &As[seg * 512]);
        }
#pragma unroll
        for (int rnd = 0; rnd < 2; ++rnd) {
            const int seg = rnd * 4 + wave;
            GLOAD_LDS16(wt + seg * 512 + lane * 8, &Ws[seg * 512]);
        }
        __syncthreads();
#pragma unroll
        for (int ks = 0; ks < 2; ++ks) {
            bf16x8 af[4], bfr[2];
#pragma unroll
            for (int i = 0; i < 4; ++i)
                af[i] = *(const bf16x8*)(&As[(rhw * 512 + ks * 256 + i * 64 + lq * 16 + l16) * 8]);
#pragma unroll
            for (int j = 0; j < 2; ++j)
                bfr[j] = *(const bf16x8*)(&Ws[(chw * 256 + ks * 128 + j * 64 + lq * 16 + l16) * 8]);
#pragma unroll
            for (int i = 0; i < 4; ++i)
#pragma unroll
                for (int j = 0; j < 2; ++j)
                    acc[i][j] = __builtin_amdgcn_mfma_f32_16x16x32_bf16(
                        af[i], bfr[j], acc[i][j], 0, 0, 0);
        }
        __syncthreads();
    }
    const int c2 = l16 & 3, g4 = (l16 >> 2) * 4;
#pragma unroll
    for (int i = 0; i < 4; ++i)
#pragma unroll
        for (int j = 0; j < 2; ++j) {
            float v0 = acc[i][j][0], v1 = acc[i][j][1];
            float v2 = acc[i][j][2], v3 = acc[i][j][3];
            QUAD_T(v0, v1, v2, v3, c2);
            const int row = row0 + wr + i * 16 + lq * 4 + c2;
            const int col = col0 + wc + j * 16 + g4;
            *(float4*)(&Out[(size_t)row * Cc + col]) = float4{v0, v1, v2, v3};
        }
}

// ---- MFMA flash attention (S^T form), causal, static-max, PAIRED q-tiles,
// double-buffered LDS (1 barrier/step), XCD-grouped (b,h). O stored in
// gemm_o's swizzled A-tile layout.
__global__ __launch_bounds__(256, 4) void attn_k(const bf16* __restrict__ QK,
                                                 const bf16* __restrict__ Vt,
                                                 bf16* __restrict__ O)
{
    __shared__ bf16 Ks[2][64 * LDS_];
    __shared__ bf16 Vs[2][64 * LDS_];
    const int tid = threadIdx.x;
    const int wv = tid >> 6, lane = tid & 63;
    const int l16 = lane & 15, lq = lane >> 4;
    // XCD swizzle: flat id -> xcd = id&7 (dispatch round-robin heuristic);
    // give each XCD 4 whole (b,h)'s so K/V is cached in ONE XCD's L2.
    const int id = blockIdx.y * 16 + blockIdx.x;        // grid (16, 32)
    const int bh = (id & 7) * 4 + (id >> 7);
    const int pi = (id >> 3) & 15;
    const int b = bh >> 4, h = bh & 15;
    const int kr = tid >> 2, c0 = (tid & 3) * 16;       // staging coords
    // permuted LDS row: key -> 32*(k>>5) + 16*((k>>2)&1) + 4*((k>>3)&3) + (k&3)
    const int pr = 32 * (kr >> 5) + 16 * ((kr >> 2) & 1) + 4 * ((kr >> 3) & 3) + (kr & 3);

    const bf16* kcol = QK + 1024 + (size_t)(b * Tt + kr) * 2048 + h * 64 + c0;
    const bf16* vcol = Vt + ((size_t)bh * 64 + kr) * Tt + c0;

    for (int phase = 0; phase < 2; ++phase) {
        const int qt = phase ? pi : (NT - 1 - pi);

        // Q B-fragments straight from global (Q pre-scaled by 0.125*log2e)
        const int qglob = qt * 64 + wv * 16 + l16;
        const bf16* qp = QK + (size_t)(b * Tt + qglob) * 2048 + h * 64;
        bf16x8 qf0 = *(const bf16x8*)(qp + lq * 8);
        bf16x8 qf1 = *(const bf16x8*)(qp + 32 + lq * 8);

        // prologue: tile 0 -> regs -> buf 0
        uint4 pk0 = *(const uint4*)(kcol);
        uint4 pk1 = *(const uint4*)(kcol + 8);
        uint4 pv0 = *(const uint4*)(vcol);
        uint4 pv1 = *(const uint4*)(vcol + 8);
        *(uint4*)(&Ks[0][pr * LDS_ + c0])     = pk0;
        *(uint4*)(&Ks[0][pr * LDS_ + c0 + 8]) = pk1;
        *(uint4*)(&Vs[0][kr * LDS_ + c0])     = pv0;
        *(uint4*)(&Vs[0][kr * LDS_ + c0 + 8]) = pv1;
        __syncthreads();

        float l = 0.f;
        f32x4 o[4];
#pragma unroll
        for (int dt = 0; dt < 4; ++dt) o[dt] = f32x4{0.f, 0.f, 0.f, 0.f};

        for (int t = 0; t <= qt; ++t) {
            const int cur = t & 1;
            if (t < qt) {                   // prefetch next tile into registers
                const bf16* kn = kcol + (size_t)(t + 1) * 64 * 2048;
                const bf16* vn = vcol + (t + 1) * 64;
                pk0 = *(const uint4*)(kn);
                pk1 = *(const uint4*)(kn + 8);
                pv0 = *(const uint4*)(vn);
                pv1 = *(const uint4*)(vn + 8);
            }

            // S^T = K Q^T : A-frag = permuted K rows, B-frag = qf
            f32x4 s[4];
#pragma unroll
            for (int mt = 0; mt < 4; ++mt) s[mt] = f32x4{0.f, 0.f, 0.f, 0.f};
#pragma unroll
            for (int mt = 0; mt < 4; ++mt) {
                bf16x8 a0 = *(const bf16x8*)(&Ks[cur][(mt * 16 + l16) * LDS_ + lq * 8]);
                s[mt] = __builtin_amdgcn_mfma_f32_16x16x32_bf16(a0, qf0, s[mt], 0, 0, 0);
            }
#pragma unroll
            for (int mt = 0; mt < 4; ++mt) {
                bf16x8 a1 = *(const bf16x8*)(&Ks[cur][(mt * 16 + l16) * LDS_ + 32 + lq * 8]);
                s[mt] = __builtin_amdgcn_mfma_f32_16x16x32_bf16(a1, qf1, s[mt], 0, 0, 0);
            }
            if (t == qt) {                  // causal mask, diagonal tile only
                const int qloc = wv * 16 + l16;
#pragma unroll
                for (int mt = 0; mt < 4; ++mt)
#pragma unroll
                    for (int r = 0; r < 4; ++r) {
                        int keyl = (mt >> 1) * 32 + lq * 8 + (mt & 1) * 4 + r;
                        if (keyl > qloc) s[mt][r] = -1e30f;
                    }
            }
            // exp2 + sum partials; C-regs become PV B-frags directly
            bf16x8 pb0, pb1;
#pragma unroll
            for (int mt = 0; mt < 4; ++mt)
#pragma unroll
                for (int r = 0; r < 4; ++r) {
                    float p = exp2f(s[mt][r]);
                    l += p;
                    s[mt][r] = p;
                }
#pragma unroll
            for (int r = 0; r < 4; ++r) {
                pb0[r]     = (bf16)s[0][r];
                pb0[4 + r] = (bf16)s[1][r];
                pb1[r]     = (bf16)s[2][r];
                pb1[4 + r] = (bf16)s[3][r];
            }
            // O^T += V^T P^T
#pragma unroll
            for (int dt = 0; dt < 4; ++dt) {
                bf16x8 v0 = *(const bf16x8*)(&Vs[cur][(dt * 16 + l16) * LDS_ + lq * 8]);
                o[dt] = __builtin_amdgcn_mfma_f32_16x16x32_bf16(v0, pb0, o[dt], 0, 0, 0);
            }
#pragma unroll
            for (int dt = 0; dt < 4; ++dt) {
                bf16x8 v1 = *(const bf16x8*)(&Vs[cur][(dt * 16 + l16) * LDS_ + 32 + lq * 8]);
                o[dt] = __builtin_amdgcn_mfma_f32_16x16x32_bf16(v1, pb1, o[dt], 0, 0, 0);
            }
            if (t < qt) {                   // commit prefetched tile to buf^1
                *(uint4*)(&Ks[cur ^ 1][pr * LDS_ + c0])     = pk0;
                *(uint4*)(&Ks[cur ^ 1][pr * LDS_ + c0 + 8]) = pk1;
                *(uint4*)(&Vs[cur ^ 1][kr * LDS_ + c0])     = pv0;
                *(uint4*)(&Vs[cur ^ 1][kr * LDS_ + c0 + 8]) = pv1;
            }
            __syncthreads();                // publish buf^1; all readers done
        }
        // softmax denom: sum partials across lq (lane bits 4,5)
        l += __shfl_xor(l, 16);
        l += __shfl_xor(l, 32);
        float inv = 1.f / l;
        // store O in gemm_o's swizzled A layout
        bf16* obase = O + ((size_t)(b * 16 + (qt >> 1)) * 16 + h) * 8192;
        const int rh = qt & 1;
#pragma unroll
        for (int dt = 0; dt < 4; ++dt) {
            bf16x4 pk;
#pragma unroll
            for (int r = 0; r < 4; ++r) pk[r] = (bf16)(o[dt][r] * inv);
            const int slot = rh * 512 + (dt >> 1) * 256 + wv * 64 +
                             ((dt & 1) * 2 + (lq >> 1)) * 16 + l16;
            *(bf16x4*)(obase + slot * 8 + (lq & 1) * 4) = pk;
        }
    }
}

extern "C" void kernel_launch(void* const* d_in, const int* in_sizes, int n_in,
                              void* d_out, int out_size, void* d_ws, size_t ws_size,
                              hipStream_t stream)
{
    const float* x    = (const float*)d_in[0];
    const float* Wq   = (const float*)d_in[1];
    const float* Wk   = (const float*)d_in[2];
    const float* Wv   = (const float*)d_in[3];
    const float* Wo   = (const float*)d_in[4];
    const float* cosb = (const float*)d_in[5];
    const float* sinb = (const float*)d_in[6];

    constexpr size_t M1 = 1024 * 1024;
    bf16* base = (bf16*)d_ws;
    bf16*   xb   = base;                    //  0..4M   swizzled x; reused attn-out
    bf16*   QK   = base + 4 * M1;           //  4M..12M [4096][2048]
    bf16*   VtG  = base + 12 * M1;          // 12M..16M [32][64][2048]
    bf16*   Wqkv = base + 16 * M1;          // 16M..19M swizzled
    bf16*   Wob  = base + 19 * M1;          // 19M..20M swizzled (64-row tiles)
    float2* csT  = (float2*)(base + 20 * M1); // 512 KB
    bf16*   Ow   = xb;

    convert_k<<<4096 + 32, 256, 0, stream>>>(x, Wq, Wk, Wv, Wo, cosb, sinb,
                                             xb, Wqkv, Wob, csT);

    gemm_qkv<<<dim3(Mrows / 128, 3072 / 128), 256, 0, stream>>>(
        xb, Wqkv, QK, VtG, csT);

    attn_k<<<dim3(NT / 2, Bb * Hh), 256, 0, stream>>>(QK, VtG, Ow);

    gemm_o<<<dim3(Mrows / 128, Cc / 64), 256, 0, stream>>>(Ow, Wob, (float*)d_out);
}